// Round 1
// baseline (248.375 us; speedup 1.0000x reference)
//
#include <hip/hip_runtime.h>
#include <hip/hip_bf16.h>
#include <cstdint>

// STFT magnitude = fused GEMM:
//   out[b,k,t] = sqrt( (basis_r[k,:]·frame[b,t,:])^2 + (basis_i[k,:]·frame[b,t,:])^2 )
// frames: 32*626 = 20032, K = 2048, k-bins = 1025 (real) + 1025 (imag).
// Stage 1: frames -> bf16 ws [20096][2048]; basis -> bf16 ws [2][1152][2048] (zero-padded).
// Stage 2: 128x128 tile MFMA GEMM (BK=64, 4 waves, global_load_lds w=16), fused magnitude.

#define FILT   2048
#define HOP    512
#define CUT    1025
#define NBATCH 32
#define TFR    626
#define NFR    (NBATCH * TFR)      // 20032
#define LSIG   320000

#define BM 128
#define BN 128
#define BK 64
#define MPAD 1152                  // 9*128 (covers 1025 k-bins)
#define MT 9
#define NT 157
#define NPAD (NT * BN)             // 20096

typedef __attribute__((ext_vector_type(8))) short short8;
typedef __attribute__((ext_vector_type(4))) float f32x4;

__device__ __forceinline__ short bf16r(float f) {
  __hip_bfloat16 h = __float2bfloat16(f);
  return __builtin_bit_cast(short, h);
}

__device__ __forceinline__ short8 pack8(float4 a, float4 b) {
  short8 v;
  v[0] = bf16r(a.x); v[1] = bf16r(a.y); v[2] = bf16r(a.z); v[3] = bf16r(a.w);
  v[4] = bf16r(b.x); v[5] = bf16r(b.y); v[6] = bf16r(b.z); v[7] = bf16r(b.w);
  return v;
}

__device__ __forceinline__ void gld_lds16(const short* g, short* l) {
  __builtin_amdgcn_global_load_lds(
      (const __attribute__((address_space(1))) uint32_t*)g,
      (__attribute__((address_space(3))) uint32_t*)l, 16, 0, 0);
}

// -------- stage 1: windowed frames (reflect pad), f32 -> bf16 --------
__global__ void build_frames(const float* __restrict__ x, short* __restrict__ F) {
  const int f = blockIdx.x;                 // 0..NPAD-1
  const size_t base = (size_t)f * FILT;
  const int i = threadIdx.x * 8;            // 256 thr * 8 = 2048
  short8 v;
  if (f >= NFR) {
    v = (short8)(short)0;
  } else {
    const int b = f / TFR, t = f - b * TFR;
    const float* xb = x + (size_t)b * LSIG;
    const int j0 = t * HOP - 1024 + i;
    if (j0 >= 0 && j0 + 8 <= LSIG) {
      float4 a = *(const float4*)(xb + j0);
      float4 c = *(const float4*)(xb + j0 + 4);
      v = pack8(a, c);
    } else {
      #pragma unroll
      for (int e = 0; e < 8; ++e) {
        int j = j0 + e;
        j = j < 0 ? -j : (j >= LSIG ? 2 * LSIG - 2 - j : j);
        v[e] = bf16r(xb[j]);
      }
    }
  }
  *(short8*)&F[base + i] = v;
}

// -------- stage 1b: basis f32 -> bf16, split real/imag, zero-pad rows --------
__global__ void convert_basis(const float* __restrict__ bs, short* __restrict__ A) {
  const int row = blockIdx.x;               // 0..2*MPAD-1
  const int p = row / MPAD;
  const int k = row - p * MPAD;
  const size_t dst = (size_t)row * FILT;
  const int i = threadIdx.x * 8;
  short8 v;
  if (k < CUT) {
    const float* src = bs + (size_t)(p * CUT + k) * FILT + i;
    float4 a = *(const float4*)src;
    float4 c = *(const float4*)(src + 4);
    v = pack8(a, c);
  } else {
    v = (short8)(short)0;
  }
  *(short8*)&A[dst + i] = v;
}

// -------- stage 2: fused GEMM + magnitude --------
template<bool USE_WS>
__global__ __launch_bounds__(256, 2)
void stft_gemm(const short* __restrict__ A, const short* __restrict__ F,
               const float* __restrict__ basis, const float* __restrict__ x,
               float* __restrict__ out)
{
  __shared__ alignas(16) short sA[2][BM][BK];   // real / imag basis tiles
  __shared__ alignas(16) short sB[BN][BK];      // frame tile

  const int tid  = threadIdx.x;
  const int wave = tid >> 6;
  const int lane = tid & 63;
  const int n0 = blockIdx.x * BN;   // frame tile
  const int m0 = blockIdx.y * BM;   // k-bin tile

  f32x4 acc_r[4][4], acc_i[4][4];
  #pragma unroll
  for (int i = 0; i < 4; ++i)
    #pragma unroll
    for (int j = 0; j < 4; ++j) { acc_r[i][j] = (f32x4)0.f; acc_i[i][j] = (f32x4)0.f; }

  const int sr = tid >> 1;           // 0..127 (reg-staged row)
  const int sh = (tid & 1) * 32;     // 0 / 32 (col half)

  for (int k0 = 0; k0 < FILT; k0 += BK) {
    if constexpr (USE_WS) {
      // 1 KiB per global_load_lds (64 lanes x 16B) = 8 rows of 64 bf16
      #pragma unroll
      for (int p = 0; p < 2; ++p) {
        #pragma unroll
        for (int cc = 0; cc < 4; ++cc) {
          const int c = wave * 4 + cc;
          const short* g = A + ((size_t)p * MPAD + (size_t)(m0 + c * 8 + (lane >> 3))) * FILT
                             + k0 + (lane & 7) * 8;
          gld_lds16(g, &sA[p][c * 8][0]);
        }
      }
      #pragma unroll
      for (int cc = 0; cc < 4; ++cc) {
        const int c = wave * 4 + cc;
        const short* g = F + (size_t)(n0 + c * 8 + (lane >> 3)) * FILT
                           + k0 + (lane & 7) * 8;
        gld_lds16(g, &sB[c * 8][0]);
      }
    } else {
      // reg-staged fallback: straight from f32 inputs
      #pragma unroll
      for (int p = 0; p < 2; ++p) {
        const int k = m0 + sr;
        short8 v[4];
        if (k < CUT) {
          const float* src = basis + (size_t)(p * CUT + k) * FILT + k0 + sh;
          #pragma unroll
          for (int q = 0; q < 4; ++q) {
            float4 a = *(const float4*)(src + q * 8);
            float4 b = *(const float4*)(src + q * 8 + 4);
            v[q] = pack8(a, b);
          }
        } else {
          #pragma unroll
          for (int q = 0; q < 4; ++q) v[q] = (short8)(short)0;
        }
        #pragma unroll
        for (int q = 0; q < 4; ++q) *(short8*)&sA[p][sr][sh + q * 8] = v[q];
      }
      {
        const int f = n0 + sr;
        short8 v[4];
        if (f < NFR) {
          const int b = f / TFR, t = f - b * TFR;
          const float* xb = x + (size_t)b * LSIG;
          const int j0 = t * HOP + k0 + sh - 1024;
          if (j0 >= 0 && j0 + 32 <= LSIG) {
            #pragma unroll
            for (int q = 0; q < 4; ++q) {
              float4 a  = *(const float4*)(xb + j0 + q * 8);
              float4 b2 = *(const float4*)(xb + j0 + q * 8 + 4);
              v[q] = pack8(a, b2);
            }
          } else {
            #pragma unroll
            for (int q = 0; q < 4; ++q)
              #pragma unroll
              for (int e = 0; e < 8; ++e) {
                int j = j0 + q * 8 + e;
                j = j < 0 ? -j : (j >= LSIG ? 2 * LSIG - 2 - j : j);
                v[q][e] = bf16r(xb[j]);
              }
          }
        } else {
          #pragma unroll
          for (int q = 0; q < 4; ++q) v[q] = (short8)(short)0;
        }
        #pragma unroll
        for (int q = 0; q < 4; ++q) *(short8*)&sB[sr][sh + q * 8] = v[q];
      }
    }
    __syncthreads();

    const int ra = lane & 15;
    #pragma unroll
    for (int kk = 0; kk < BK; kk += 32) {
      const int col = kk + (lane >> 4) * 8;
      short8 ar[4], ai[4], bfr[4];
      #pragma unroll
      for (int i = 0; i < 4; ++i) {
        const int rm = (wave >> 1) * 64 + i * 16 + ra;
        ar[i] = *(const short8*)&sA[0][rm][col];
        ai[i] = *(const short8*)&sA[1][rm][col];
        const int rn = (wave & 1) * 64 + i * 16 + ra;
        bfr[i] = *(const short8*)&sB[rn][col];
      }
      #pragma unroll
      for (int i = 0; i < 4; ++i)
        #pragma unroll
        for (int j = 0; j < 4; ++j) {
          acc_r[i][j] = __builtin_amdgcn_mfma_f32_16x16x32_bf16(ar[i], bfr[j], acc_r[i][j], 0, 0, 0);
          acc_i[i][j] = __builtin_amdgcn_mfma_f32_16x16x32_bf16(ai[i], bfr[j], acc_i[i][j], 0, 0, 0);
        }
    }
    __syncthreads();
  }

  // epilogue: magnitude + guarded write. C/D: col=lane&15, row=(lane>>4)*4+reg
  const int wm0 = m0 + (wave >> 1) * 64;
  const int wn0 = n0 + (wave & 1) * 64;
  const int cl = lane & 15;
  const int rg = (lane >> 4) * 4;
  #pragma unroll
  for (int j = 0; j < 4; ++j) {
    const int f = wn0 + j * 16 + cl;
    if (f >= NFR) continue;
    const int b = f / TFR, t = f - b * TFR;
    float* ob = out + (size_t)b * (CUT * TFR) + t;
    #pragma unroll
    for (int i = 0; i < 4; ++i) {
      #pragma unroll
      for (int r = 0; r < 4; ++r) {
        const int k = wm0 + i * 16 + rg + r;
        if (k < CUT) {
          float re = acc_r[i][j][r], im = acc_i[i][j][r];
          ob[(size_t)k * TFR] = sqrtf(re * re + im * im);
        }
      }
    }
  }
}

extern "C" void kernel_launch(void* const* d_in, const int* in_sizes, int n_in,
                              void* d_out, int out_size, void* d_ws, size_t ws_size,
                              hipStream_t stream) {
  const float* x     = (const float*)d_in[0];
  const float* basis = (const float*)d_in[1];
  float* out = (float*)d_out;

  const size_t fbytes = (size_t)NPAD * FILT * sizeof(short);       // 82,313,216
  const size_t abytes = (size_t)2 * MPAD * FILT * sizeof(short);   //  9,437,184

  dim3 grid(NT, MT);
  if (ws_size >= fbytes + abytes) {
    short* F = (short*)d_ws;
    short* A = (short*)((char*)d_ws + fbytes);
    build_frames<<<NPAD, 256, 0, stream>>>(x, F);
    convert_basis<<<2 * MPAD, 256, 0, stream>>>(basis, A);
    stft_gemm<true><<<grid, 256, 0, stream>>>(A, F, nullptr, nullptr, out);
  } else {
    stft_gemm<false><<<grid, 256, 0, stream>>>(nullptr, nullptr, basis, x, out);
  }
}